// Round 6
// baseline (340.665 us; speedup 1.0000x reference)
//
#include <hip/hip_runtime.h>

#define N_NODES 100000
#define N_EDGES 1200000
#define IN_F 128
#define HID 64
#define BN_EPS 1e-5f
#define SCAN_NBLK 98   // 98 * 1024 >= 100000
#define E4 (N_EDGES / 4)
#define K1B 1172       // ceil(E4/256): K1 blocks (4 edges/thread + stats stride)
#define FB 586         // fill blocks: 8 edges (2 int4) per thread
#define GEMM_B 1563    // ceil(100000/64)

typedef unsigned int uint;
typedef unsigned short ushort;
typedef __attribute__((ext_vector_type(8))) short bf16x8;
typedef __attribute__((ext_vector_type(4))) float f32x4;

__device__ inline uint f2bf(float f) {        // f32 -> bf16 (RNE), low 16 bits
    uint u = __float_as_uint(f);
    return (u + 0x7fffu + ((u >> 16) & 1u)) >> 16;
}
__device__ inline float bflo(uint v) { return __uint_as_float(v << 16); }
__device__ inline float bfhi(uint v) { return __uint_as_float(v & 0xffff0000u); }

// ---------------- K1: per-thread fused hist atomics (issue-early) + stats(x) ----------------
__global__ __launch_bounds__(256) void k_hist_stats(
    const int4* __restrict__ dst4, int* __restrict__ cnt, int4* __restrict__ rank4,
    const float4* __restrict__ x4, float* __restrict__ sums) {
    __shared__ float lds[4][32][8];
    int t = threadIdx.x;
    int i = blockIdx.x * 256 + t;
    bool vi = i < E4;
    int4 d, r;
    if (vi) {
        d = dst4[i];
        r.x = atomicAdd(&cnt[d.x], 1);   // 4 atomic-returns in flight...
        r.y = atomicAdd(&cnt[d.y], 1);
        r.z = atomicAdd(&cnt[d.z], 1);
        r.w = atomicAdd(&cnt[d.w], 1);
    }
    // ...hidden under the stats row loop
    int cq = t & 31, rs = t >> 5;
    float s1[4] = {0.f, 0.f, 0.f, 0.f}, s2[4] = {0.f, 0.f, 0.f, 0.f};
    for (int row = blockIdx.x * 8 + rs; row < N_NODES; row += K1B * 8) {
        float4 v = x4[(size_t)row * 32 + cq];
        s1[0] += v.x; s2[0] += v.x * v.x;
        s1[1] += v.y; s2[1] += v.y * v.y;
        s1[2] += v.z; s2[2] += v.z * v.z;
        s1[3] += v.w; s2[3] += v.w * v.w;
    }
    if (vi) rank4[i] = r;
#pragma unroll
    for (int j = 0; j < 4; j++) {
        s1[j] += __shfl_xor(s1[j], 32);
        s2[j] += __shfl_xor(s2[j], 32);
    }
    int w = t >> 6;
    if ((t & 63) < 32) {
#pragma unroll
        for (int j = 0; j < 4; j++) {
            lds[w][cq][j] = s1[j];
            lds[w][cq][4 + j] = s2[j];
        }
    }
    __syncthreads();
    {
        int cq2 = t >> 3, k = t & 7;
        float v = lds[0][cq2][k] + lds[1][cq2][k] + lds[2][cq2][k] + lds[3][cq2][k];
        int col = cq2 * 4 + (k & 3);
        atomicAdd(&sums[(k >> 2) * 128 + col], v);
    }
}

// ---------------- scan ----------------
__global__ void k_scan_block(const int* __restrict__ cnt, int* __restrict__ outv,
                             int* __restrict__ bsum, float* __restrict__ dinv) {
    __shared__ int lds[256];
    int t = threadIdx.x;
    int base = blockIdx.x * 1024 + t * 4;
    int v[4];
#pragma unroll
    for (int q = 0; q < 4; q++) {
        int idx = base + q;
        v[q] = (idx < N_NODES) ? cnt[idx] : 0;
        if (idx < N_NODES) dinv[idx] = rsqrtf((float)(v[q] + 1));
    }
    int tot = v[0] + v[1] + v[2] + v[3];
    lds[t] = tot;
    __syncthreads();
    int x = tot;
    for (int off = 1; off < 256; off <<= 1) {
        int y = (t >= off) ? lds[t - off] : 0;
        __syncthreads();
        x += y;
        lds[t] = x;
        __syncthreads();
    }
    int run = x - tot;
    if (t == 255) bsum[blockIdx.x] = x;
#pragma unroll
    for (int q = 0; q < 4; q++) {
        int idx = base + q;
        if (idx < N_NODES) outv[idx] = run;
        run += v[q];
    }
}

// block-sum scan done redundantly per block (392B) -> one launch saved
__global__ void k_scan_add(int* __restrict__ row_ptr, const int* __restrict__ bsum) {
    __shared__ int sb[256];
    int t = threadIdx.x;
    int v = (t < SCAN_NBLK) ? bsum[t] : 0;
    sb[t] = v;
    __syncthreads();
    int x = v;
    for (int off = 1; off < 256; off <<= 1) {
        int y = (t >= off) ? sb[t - off] : 0;
        __syncthreads();
        x += y;
        sb[t] = x;
        __syncthreads();
    }
    int i = blockIdx.x * 256 + t;
    if (i < N_NODES) {
        int blk = i >> 10;
        int off = blk ? sb[blk - 1] : 0;
        row_ptr[i] += off;
    }
    if (i == 0) row_ptr[N_NODES] = N_EDGES;
}

// ---------------- MFMA GEMM body ----------------
// LAYER0: A = f32 x (convert in staging); out = relu(acc+bias) bf16; fused stats->sums_out.
// else:   A = bf16 h; out = acc * dinv[row] bf16 (t matrix).
template <int K, bool LAYER0>
__device__ __forceinline__ void gemm_body(
    int bid, const ushort* __restrict__ h, const float* __restrict__ xf,
    const float* __restrict__ W, const float* __restrict__ sums,
    const float* __restrict__ gamma, const float* __restrict__ beta,
    const float* __restrict__ bias, const float* __restrict__ dinv,
    ushort* __restrict__ out, float* __restrict__ sums_out) {
    __shared__ ushort Alds[64 * K];
    __shared__ ushort Wt[64 * K];
    __shared__ float scale_s[K], shift_s[K], shW[HID];
    __shared__ float sred[4][128];
    const int KB = K * 2;
    int t = threadIdx.x;
    if (t < K) {
        float m = sums[t] * (1.0f / N_NODES);
        float var = sums[K + t] * (1.0f / N_NODES) - m * m;
        float sc = gamma[t] * rsqrtf(var + BN_EPS);
        scale_s[t] = sc;
        shift_s[t] = beta[t] - m * sc;
    }
    __syncthreads();
    for (int idx = t; idx < K * 64; idx += 256) {
        int k = idx >> 6, n = idx & 63;
        float v = W[idx] * scale_s[k];
        int byte = n * KB + k * 2;
        byte ^= ((n & 7) << 4);
        *(ushort*)((char*)Wt + byte) = (ushort)f2bf(v);
    }
    if (t < HID) {
        float acc = 0.f;
#pragma unroll 4
        for (int k = 0; k < K; k++) acc += shift_s[k] * W[k * HID + t];
        shW[t] = acc;
    }
    int row0 = bid * 64;
    if (LAYER0) {
        // stage f32 x -> bf16 LDS (16B groups preserved for swizzle)
        for (int idx = t; idx < 64 * 16; idx += 256) {
            int r = idx >> 4, kg = idx & 15;
            int rr = row0 + r;
            if (rr >= N_NODES) rr = N_NODES - 1;
            const float* p = xf + (size_t)rr * 128 + kg * 8;
            float4 a = *(const float4*)p;
            float4 b = *(const float4*)(p + 4);
            uint4 v;
            v.x = f2bf(a.x) | (f2bf(a.y) << 16);
            v.y = f2bf(a.z) | (f2bf(a.w) << 16);
            v.z = f2bf(b.x) | (f2bf(b.y) << 16);
            v.w = f2bf(b.z) | (f2bf(b.w) << 16);
            int byte = (r * KB + kg * 16) ^ ((r & 7) << 4);
            *(uint4*)((char*)Alds + byte) = v;
        }
    } else {
        const int KG = K / 8;
        for (int idx = t; idx < 64 * KG; idx += 256) {
            int r = idx / KG, kg = idx % KG;
            int rr = row0 + r;
            if (rr >= N_NODES) rr = N_NODES - 1;
            uint4 v = *(const uint4*)(h + (size_t)rr * K + kg * 8);
            int byte = (r * KB + kg * 16) ^ ((r & 7) << 4);
            *(uint4*)((char*)Alds + byte) = v;
        }
    }
    __syncthreads();

    int w = t >> 6, l = t & 63;
    int lr = l & 15, lg = l >> 4;
    f32x4 acc[4];
#pragma unroll
    for (int nt = 0; nt < 4; nt++) {
        float s = shW[nt * 16 + lr];
        acc[nt] = (f32x4){s, s, s, s};
    }
#pragma unroll
    for (int c = 0; c < K / 32; c++) {
        int arow = w * 16 + lr;
        int abyte = (arow * KB + c * 64 + lg * 16) ^ ((arow & 7) << 4);
        bf16x8 a = *(const bf16x8*)((const char*)Alds + abyte);
#pragma unroll
        for (int nt = 0; nt < 4; nt++) {
            int n = nt * 16 + lr;
            int bbyte = (n * KB + c * 64 + lg * 16) ^ ((n & 7) << 4);
            bf16x8 b = *(const bf16x8*)((const char*)Wt + bbyte);
            acc[nt] = __builtin_amdgcn_mfma_f32_16x16x32_bf16(a, b, acc[nt], 0, 0, 0);
        }
    }
    int wrow0 = row0 + w * 16;
    char* myA = (char*)Alds + w * 16 * KB;
    float4 dv = {0.f, 0.f, 0.f, 0.f};
    float bias_v[4];
    if (LAYER0) {
#pragma unroll
        for (int nt = 0; nt < 4; nt++) bias_v[nt] = bias[nt * 16 + lr];
    } else {
        int dbase = wrow0 + lg * 4;
        if (dbase > N_NODES - 4) dbase = N_NODES - 4;
        dv = *(const float4*)(dinv + dbase);
    }
    float dvv[4] = {dv.x, dv.y, dv.z, dv.w};
    float st1[4] = {0.f, 0.f, 0.f, 0.f}, st2[4] = {0.f, 0.f, 0.f, 0.f};
#pragma unroll
    for (int nt = 0; nt < 4; nt++) {
#pragma unroll
        for (int r = 0; r < 4; r++) {
            float v = acc[nt][r];
            if (LAYER0) {
                v = fmaxf(v + bias_v[nt], 0.f);
                if (wrow0 + lg * 4 + r < N_NODES) {   // mask clamped pad rows out of stats
                    st1[nt] += v;
                    st2[nt] += v * v;
                }
            } else {
                v = v * dvv[r];
            }
            int rowl = lg * 4 + r;
            int byte = (rowl * 128 + (nt * 16 + lr) * 2) ^ ((rowl & 7) << 4);
            *(ushort*)(myA + byte) = (ushort)f2bf(v);
        }
    }
    {
        int rowl0 = l >> 3, kg0 = l & 7;
        int b0 = (rowl0 * 128 + kg0 * 16) ^ ((rowl0 & 7) << 4);
        int rowl1 = 8 + (l >> 3);
        int b1 = (rowl1 * 128 + kg0 * 16) ^ ((rowl1 & 7) << 4);
        uint4 v0 = *(uint4*)(myA + b0);
        uint4 v1 = *(uint4*)(myA + b1);
        size_t gg = (size_t)wrow0 * 128 + l * 16;
        if (wrow0 + rowl0 < N_NODES) *(uint4*)((char*)out + gg) = v0;
        if (wrow0 + rowl1 < N_NODES) *(uint4*)((char*)out + gg + 1024) = v1;
    }
    if (LAYER0) {   // fused column stats of this block's h0 tile
#pragma unroll
        for (int nt = 0; nt < 4; nt++) {
            st1[nt] += __shfl_xor(st1[nt], 16);
            st1[nt] += __shfl_xor(st1[nt], 32);
            st2[nt] += __shfl_xor(st2[nt], 16);
            st2[nt] += __shfl_xor(st2[nt], 32);
        }
        if (l < 16) {
#pragma unroll
            for (int nt = 0; nt < 4; nt++) {
                sred[w][nt * 16 + l] = st1[nt];
                sred[w][64 + nt * 16 + l] = st2[nt];
            }
        }
        __syncthreads();
        if (t < 128) {
            float v = sred[0][t] + sred[1][t] + sred[2][t] + sred[3][t];
            atomicAdd(&sums_out[t], v);
        }
    }
}

// ---------------- fused: CSR fill || gemm0(+stats) ----------------
__global__ __launch_bounds__(256) void k_fill_gemm0(
    const int4* __restrict__ src4, const int4* __restrict__ dst4,
    const int4* __restrict__ rank4, const int* __restrict__ row_ptr,
    int* __restrict__ col, const float* __restrict__ x, const float* __restrict__ W0,
    const float* __restrict__ sums0, const float* __restrict__ gamma,
    const float* __restrict__ beta, const float* __restrict__ bias,
    ushort* __restrict__ h0, float* __restrict__ sums1) {
    if (blockIdx.x < FB) {
        int t = threadIdx.x;
#pragma unroll
        for (int p = 0; p < 2; p++) {
            int i = blockIdx.x * 512 + t + p * 256;
            if (i < E4) {
                int4 s = src4[i];
                int4 d = dst4[i];
                int4 r = rank4[i];
                col[row_ptr[d.x] + r.x] = s.x;
                col[row_ptr[d.y] + r.y] = s.y;
                col[row_ptr[d.z] + r.z] = s.z;
                col[row_ptr[d.w] + r.w] = s.w;
            }
        }
        return;
    }
    gemm_body<IN_F, true>(blockIdx.x - FB, nullptr, x, W0, sums0, gamma, beta, bias,
                          nullptr, h0, sums1);
}

__global__ __launch_bounds__(256) void k_gemm64(
    const ushort* __restrict__ h, const float* __restrict__ W,
    const float* __restrict__ sums, const float* __restrict__ gamma,
    const float* __restrict__ beta, const float* __restrict__ dinv,
    ushort* __restrict__ out) {
    gemm_body<HID, false>(blockIdx.x, h, nullptr, W, sums, gamma, beta, nullptr, dinv,
                          out, nullptr);
}

// ---------------- stats on bf16 h (C=64) ----------------
__global__ __launch_bounds__(256) void k_stats_h(const uint4* __restrict__ h4,
                                                 float* __restrict__ sums) {
    __shared__ float lds[4][8][16];
    int t = threadIdx.x;
    int cg = t & 7, rs = t >> 3;
    float s1[8], s2[8];
#pragma unroll
    for (int j = 0; j < 8; j++) { s1[j] = 0.f; s2[j] = 0.f; }
    for (int r = blockIdx.x * 32 + rs; r < N_NODES; r += gridDim.x * 32) {
        uint4 v = h4[(size_t)r * 8 + cg];
        float f;
        f = bflo(v.x); s1[0] += f; s2[0] += f * f;
        f = bfhi(v.x); s1[1] += f; s2[1] += f * f;
        f = bflo(v.y); s1[2] += f; s2[2] += f * f;
        f = bfhi(v.y); s1[3] += f; s2[3] += f * f;
        f = bflo(v.z); s1[4] += f; s2[4] += f * f;
        f = bfhi(v.z); s1[5] += f; s2[5] += f * f;
        f = bflo(v.w); s1[6] += f; s2[6] += f * f;
        f = bfhi(v.w); s1[7] += f; s2[7] += f * f;
    }
#pragma unroll
    for (int off = 8; off <= 32; off <<= 1) {
#pragma unroll
        for (int j = 0; j < 8; j++) {
            s1[j] += __shfl_xor(s1[j], off);
            s2[j] += __shfl_xor(s2[j], off);
        }
    }
    int w = t >> 6;
    if ((t & 63) < 8) {
#pragma unroll
        for (int j = 0; j < 8; j++) {
            lds[w][cg][j] = s1[j];
            lds[w][cg][8 + j] = s2[j];
        }
    }
    __syncthreads();
    if (t < 128) {
        int cg2 = t >> 4, k = t & 15;
        float v = lds[0][cg2][k] + lds[1][cg2][k] + lds[2][cg2][k] + lds[3][cg2][k];
        int col = cg2 * 8 + (k & 7);
        atomicAdd(&sums[(k >> 3) * 64 + col], v);
    }
}

// ---------------- per-node gather aggregation (bf16 rows, shfl-broadcast col) ----------------
template <bool OUT_BF16>
__global__ __launch_bounds__(256) void k_agg(const uint4* __restrict__ t4,
                                             const int* __restrict__ row_ptr,
                                             const int* __restrict__ col,
                                             const float* __restrict__ dinv,
                                             const float* __restrict__ bias,
                                             void* __restrict__ out) {
    int wid = (blockIdx.x * 256 + threadIdx.x) >> 6;
    int lane = threadIdx.x & 63;
    int g = lane >> 3, q = lane & 7;
    if (wid >= N_NODES) return;
    int e0 = row_ptr[wid], e1 = row_ptr[wid + 1];
    int deg = e1 - e0;
    int ce = e0 + lane;
    int cidx = col[(ce < e1) ? ce : 0];   // one coalesced load covers 64 edges
    float a[8] = {0.f, 0.f, 0.f, 0.f, 0.f, 0.f, 0.f, 0.f};
    uint4 selfv = {0, 0, 0, 0};
    if (g == 0) selfv = t4[(size_t)wid * 8 + q];
    int degc = deg < 64 ? deg : 64;
    for (int d = 0; d < degc; d += 32) {
        int s[4];
        bool val[4];
#pragma unroll
        for (int j = 0; j < 4; j++) {
            int idx = d + j * 8 + g;
            val[j] = idx < degc;
            s[j] = __shfl(cidx, idx & 63);
        }
        uint4 v[4];
#pragma unroll
        for (int j = 0; j < 4; j++)
            v[j] = t4[(size_t)(val[j] ? s[j] : wid) * 8 + q];  // 4 gathers in flight
#pragma unroll
        for (int j = 0; j < 4; j++) {
            if (val[j]) {
                a[0] += bflo(v[j].x); a[1] += bfhi(v[j].x);
                a[2] += bflo(v[j].y); a[3] += bfhi(v[j].y);
                a[4] += bflo(v[j].z); a[5] += bfhi(v[j].z);
                a[6] += bflo(v[j].w); a[7] += bfhi(v[j].w);
            }
        }
    }
    for (int base = e0 + 64; base < e1; base += 8) {
        int ee = base + g;
        if (ee < e1) {
            int s = col[ee];
            uint4 v = t4[(size_t)s * 8 + q];
            a[0] += bflo(v.x); a[1] += bfhi(v.x);
            a[2] += bflo(v.y); a[3] += bfhi(v.y);
            a[4] += bflo(v.z); a[5] += bfhi(v.z);
            a[6] += bflo(v.w); a[7] += bfhi(v.w);
        }
    }
    if (g == 0) {
        a[0] += bflo(selfv.x); a[1] += bfhi(selfv.x);
        a[2] += bflo(selfv.y); a[3] += bfhi(selfv.y);
        a[4] += bflo(selfv.z); a[5] += bfhi(selfv.z);
        a[6] += bflo(selfv.w); a[7] += bfhi(selfv.w);
    }
#pragma unroll
    for (int off = 8; off <= 32; off <<= 1) {
#pragma unroll
        for (int j = 0; j < 8; j++) a[j] += __shfl_xor(a[j], off);
    }
    if (g == 0) {
        float di = dinv[wid];
        float4 b0v = reinterpret_cast<const float4*>(bias)[q * 2];
        float4 b1v = reinterpret_cast<const float4*>(bias)[q * 2 + 1];
        float r[8];
        r[0] = fmaxf(di * a[0] + b0v.x, 0.f);
        r[1] = fmaxf(di * a[1] + b0v.y, 0.f);
        r[2] = fmaxf(di * a[2] + b0v.z, 0.f);
        r[3] = fmaxf(di * a[3] + b0v.w, 0.f);
        r[4] = fmaxf(di * a[4] + b1v.x, 0.f);
        r[5] = fmaxf(di * a[5] + b1v.y, 0.f);
        r[6] = fmaxf(di * a[6] + b1v.z, 0.f);
        r[7] = fmaxf(di * a[7] + b1v.w, 0.f);
        if (OUT_BF16) {
            uint4 o;
            o.x = f2bf(r[0]) | (f2bf(r[1]) << 16);
            o.y = f2bf(r[2]) | (f2bf(r[3]) << 16);
            o.z = f2bf(r[4]) | (f2bf(r[5]) << 16);
            o.w = f2bf(r[6]) | (f2bf(r[7]) << 16);
            ((uint4*)out)[(size_t)wid * 8 + q] = o;
        } else {
            float4* orow = (float4*)((float*)out + (size_t)wid * HID + q * 8);
            orow[0] = (float4){r[0], r[1], r[2], r[3]};
            orow[1] = (float4){r[4], r[5], r[6], r[7]};
        }
    }
}

// ---------------- launch ----------------

extern "C" void kernel_launch(void* const* d_in, const int* in_sizes, int n_in,
                              void* d_out, int out_size, void* d_ws, size_t ws_size,
                              hipStream_t stream) {
    const float* x = (const float*)d_in[0];
    const int* ei = (const int*)d_in[1];
    const int4* src4 = (const int4*)ei;
    const int4* dst4 = (const int4*)(ei + N_EDGES);
    const float* bn0_g = (const float*)d_in[2];
    const float* bn0_b = (const float*)d_in[3];
    const float* W0 = (const float*)d_in[4];
    const float* b0 = (const float*)d_in[5];
    const float* bns_g = (const float*)d_in[6];
    const float* bns_b = (const float*)d_in[7];
    const float* Ws = (const float*)d_in[8];
    const float* bs = (const float*)d_in[9];
    float* out = (float*)d_out;
    char* ws = (char*)d_ws;

    // workspace layout (bytes)
    float*  dinv    = (float*)(ws + 0);          //   400,128
    int*    cnt     = (int*)(ws + 400128);       //   400,128
    int*    row_ptr = (int*)(ws + 800256);       //   400,384
    int*    col     = (int*)(ws + 1200640);      // 4,800,000
    int*    bsum    = (int*)(ws + 6000640);      //       512
    float*  sums    = (float*)(ws + 6001152);    //     2,560
    int*    rank    = (int*)(ws + 6003712);      // 4,800,000
    ushort* h0      = (ushort*)(ws + 10803712);  // 12,800,000
    ushort* h1      = (ushort*)(ws + 23603712);  // 12,800,000
    ushort* tbuf    = (ushort*)(ws + 36403712);  // 12,800,000 -> 49.2MB total
    ushort* h2      = h0;                        // h0 dead after gemm1
    float* sums0 = sums;          // 256 floats (IN_F)
    float* sums1 = sums + 256;    // 128
    float* sums2 = sums + 384;    // 128
    float* sums3 = sums + 512;    // 128

    const int NB = (N_NODES + 255) / 256;     // 391
    const int AGG_B = (N_NODES + 3) / 4;      // 25000

    hipMemsetAsync(cnt, 0, N_NODES * sizeof(int), stream);
    hipMemsetAsync(sums, 0, 640 * sizeof(float), stream);

    // ---- K1: hist atomics issue-early + stats(x) in the same threads ----
    k_hist_stats<<<K1B, 256, 0, stream>>>(dst4, cnt, (int4*)rank, (const float4*)x, sums0);
    // ---- scan (2 launches) ----
    k_scan_block<<<SCAN_NBLK, 256, 0, stream>>>(cnt, row_ptr, bsum, dinv);
    k_scan_add<<<NB, 256, 0, stream>>>(row_ptr, bsum);

    // ---- K3: CSR fill || gemm0 (BN+Linear+ReLU -> h0 bf16, + fused stats -> sums1) ----
    k_fill_gemm0<<<FB + GEMM_B, 256, 0, stream>>>(src4, dst4, (const int4*)rank, row_ptr,
                                                  col, x, W0, sums0, bn0_g, bn0_b, b0,
                                                  h0, sums1);

    // ---- layer 1 ----
    k_gemm64<<<GEMM_B, 256, 0, stream>>>(h0, Ws, sums1, bns_g, bns_b, dinv, tbuf);
    k_agg<true><<<AGG_B, 256, 0, stream>>>((const uint4*)tbuf, row_ptr, col, dinv, bs, h1);

    // ---- layer 2 ----
    k_stats_h<<<400, 256, 0, stream>>>((const uint4*)h1, sums2);
    k_gemm64<<<GEMM_B, 256, 0, stream>>>(h1, Ws + HID * HID, sums2, bns_g + HID,
                                         bns_b + HID, dinv, tbuf);
    k_agg<true><<<AGG_B, 256, 0, stream>>>((const uint4*)tbuf, row_ptr, col, dinv,
                                           bs + HID, h2);

    // ---- layer 3 (f32 out) ----
    k_stats_h<<<400, 256, 0, stream>>>((const uint4*)h2, sums3);
    k_gemm64<<<GEMM_B, 256, 0, stream>>>(h2, Ws + 2 * HID * HID, sums3, bns_g + 2 * HID,
                                         bns_b + 2 * HID, dinv, tbuf);
    k_agg<false><<<AGG_B, 256, 0, stream>>>((const uint4*)tbuf, row_ptr, col, dinv,
                                            bs + 2 * HID, out);
}

// Round 7
// 284.553 us; speedup vs baseline: 1.1972x; 1.1972x over previous
//
#include <hip/hip_runtime.h>

#define N_NODES 100000
#define N_EDGES 1200000
#define IN_F 128
#define HID 64
#define BN_EPS 1e-5f
#define E4 (N_EDGES / 4)
#define NBKT 391       // ceil(100000/256) buckets; bucket = dst >> 8
#define BSLOT 4096     // slots per bucket region (mean 3070, +18 sigma safe)
#define NBB 293        // bucket-scatter blocks: 293*1024 edges-slots >= 1.2M
#define SB 500         // stats_in virtual blocks
#define GEMM_B 1563    // ceil(100000/64)

typedef unsigned int uint;
typedef unsigned short ushort;
typedef __attribute__((ext_vector_type(8))) short bf16x8;
typedef __attribute__((ext_vector_type(4))) float f32x4;

__device__ inline uint f2bf(float f) {        // f32 -> bf16 (RNE), low 16 bits
    uint u = __float_as_uint(f);
    return (u + 0x7fffu + ((u >> 16) & 1u)) >> 16;
}
__device__ inline float bflo(uint v) { return __uint_as_float(v << 16); }
__device__ inline float bfhi(uint v) { return __uint_as_float(v & 0xffff0000u); }

// ---------------- K_B: bucket counting-sort scatter || stats(x) ----------------
// Edge blocks: LDS hist over 391 buckets, 1 global atomic per (block,bucket),
// scatter (src,dst) pairs into fixed bucket regions (contiguous per block).
__global__ __launch_bounds__(256) void k_bucket_stats(
    const int4* __restrict__ src4, const int4* __restrict__ dst4,
    int* __restrict__ cursor, int2* __restrict__ pairs,
    const float4* __restrict__ x4, float* __restrict__ sums) {
    int t = threadIdx.x;
    if (blockIdx.x < NBB) {
        __shared__ int cnt_l[NBKT];
        __shared__ int base_l[NBKT];
        for (int i = t; i < NBKT; i += 256) cnt_l[i] = 0;
        __syncthreads();
        int4 d[4];
        int bk[16], rk[16];
#pragma unroll
        for (int k = 0; k < 4; k++) {
            int idx = blockIdx.x * 1024 + k * 256 + t;
            if (idx < E4) {
                int4 dv = dst4[idx];
                d[k] = dv;
                bk[k * 4 + 0] = dv.x >> 8;
                bk[k * 4 + 1] = dv.y >> 8;
                bk[k * 4 + 2] = dv.z >> 8;
                bk[k * 4 + 3] = dv.w >> 8;
                rk[k * 4 + 0] = atomicAdd(&cnt_l[bk[k * 4 + 0]], 1);
                rk[k * 4 + 1] = atomicAdd(&cnt_l[bk[k * 4 + 1]], 1);
                rk[k * 4 + 2] = atomicAdd(&cnt_l[bk[k * 4 + 2]], 1);
                rk[k * 4 + 3] = atomicAdd(&cnt_l[bk[k * 4 + 3]], 1);
            }
        }
        __syncthreads();
        for (int i = t; i < NBKT; i += 256) {
            int c = cnt_l[i];
            base_l[i] = c ? atomicAdd(&cursor[i], c) : 0;
        }
        __syncthreads();
#pragma unroll
        for (int k = 0; k < 4; k++) {
            int idx = blockIdx.x * 1024 + k * 256 + t;
            if (idx < E4) {
                int4 sv = src4[idx];
                int b0 = bk[k * 4 + 0], b1 = bk[k * 4 + 1];
                int b2 = bk[k * 4 + 2], b3 = bk[k * 4 + 3];
                pairs[b0 * BSLOT + base_l[b0] + rk[k * 4 + 0]] = (int2){sv.x, d[k].x};
                pairs[b1 * BSLOT + base_l[b1] + rk[k * 4 + 1]] = (int2){sv.y, d[k].y};
                pairs[b2 * BSLOT + base_l[b2] + rk[k * 4 + 2]] = (int2){sv.z, d[k].z};
                pairs[b3 * BSLOT + base_l[b3] + rk[k * 4 + 3]] = (int2){sv.w, d[k].w};
            }
        }
        return;
    }
    // ---- stats(x) path ----
    __shared__ float lds[4][32][8];
    int vb = blockIdx.x - NBB;
    int cq = t & 31, rs = t >> 5;
    float s1[4] = {0.f, 0.f, 0.f, 0.f}, s2[4] = {0.f, 0.f, 0.f, 0.f};
    for (int row = vb * 8 + rs; row < N_NODES; row += SB * 8) {
        float4 v = x4[(size_t)row * 32 + cq];
        s1[0] += v.x; s2[0] += v.x * v.x;
        s1[1] += v.y; s2[1] += v.y * v.y;
        s1[2] += v.z; s2[2] += v.z * v.z;
        s1[3] += v.w; s2[3] += v.w * v.w;
    }
#pragma unroll
    for (int j = 0; j < 4; j++) {
        s1[j] += __shfl_xor(s1[j], 32);
        s2[j] += __shfl_xor(s2[j], 32);
    }
    int w = t >> 6;
    if ((t & 63) < 32) {
#pragma unroll
        for (int j = 0; j < 4; j++) {
            lds[w][cq][j] = s1[j];
            lds[w][cq][4 + j] = s2[j];
        }
    }
    __syncthreads();
    {
        int cq2 = t >> 3, k = t & 7;
        float v = lds[0][cq2][k] + lds[1][cq2][k] + lds[2][cq2][k] + lds[3][cq2][k];
        int col = cq2 * 4 + (k & 3);
        atomicAdd(&sums[(k >> 2) * 128 + col], v);
    }
}

// ---------------- tiny scan over 391 bucket totals ----------------
__global__ __launch_bounds__(512) void k_scan_bkt(const int* __restrict__ cursor,
                                                  int* __restrict__ bucketBase,
                                                  int* __restrict__ row_ptr) {
    __shared__ int sb[512];
    int t = threadIdx.x;
    int v = (t < NBKT) ? cursor[t] : 0;
    sb[t] = v;
    __syncthreads();
    int x = v;
    for (int off = 1; off < 512; off <<= 1) {
        int y = (t >= off) ? sb[t - off] : 0;
        __syncthreads();
        x += y;
        sb[t] = x;
        __syncthreads();
    }
    if (t <= NBKT) bucketBase[t] = x - v;   // exclusive prefix; t==NBKT -> total
    if (t == 0) row_ptr[N_NODES] = N_EDGES;
}

// ---------------- MFMA GEMM body (unchanged from R6) ----------------
template <int K, bool LAYER0>
__device__ __forceinline__ void gemm_body(
    int bid, const ushort* __restrict__ h, const float* __restrict__ xf,
    const float* __restrict__ W, const float* __restrict__ sums,
    const float* __restrict__ gamma, const float* __restrict__ beta,
    const float* __restrict__ bias, const float* __restrict__ dinv,
    ushort* __restrict__ out, float* __restrict__ sums_out) {
    __shared__ ushort Alds[64 * K];
    __shared__ ushort Wt[64 * K];
    __shared__ float scale_s[K], shift_s[K], shW[HID];
    __shared__ float sred[4][128];
    const int KB = K * 2;
    int t = threadIdx.x;
    if (t < K) {
        float m = sums[t] * (1.0f / N_NODES);
        float var = sums[K + t] * (1.0f / N_NODES) - m * m;
        float sc = gamma[t] * rsqrtf(var + BN_EPS);
        scale_s[t] = sc;
        shift_s[t] = beta[t] - m * sc;
    }
    __syncthreads();
    for (int idx = t; idx < K * 64; idx += 256) {
        int k = idx >> 6, n = idx & 63;
        float v = W[idx] * scale_s[k];
        int byte = n * KB + k * 2;
        byte ^= ((n & 7) << 4);
        *(ushort*)((char*)Wt + byte) = (ushort)f2bf(v);
    }
    if (t < HID) {
        float acc = 0.f;
#pragma unroll 4
        for (int k = 0; k < K; k++) acc += shift_s[k] * W[k * HID + t];
        shW[t] = acc;
    }
    int row0 = bid * 64;
    if (LAYER0) {
        for (int idx = t; idx < 64 * 16; idx += 256) {
            int r = idx >> 4, kg = idx & 15;
            int rr = row0 + r;
            if (rr >= N_NODES) rr = N_NODES - 1;
            const float* p = xf + (size_t)rr * 128 + kg * 8;
            float4 a = *(const float4*)p;
            float4 b = *(const float4*)(p + 4);
            uint4 v;
            v.x = f2bf(a.x) | (f2bf(a.y) << 16);
            v.y = f2bf(a.z) | (f2bf(a.w) << 16);
            v.z = f2bf(b.x) | (f2bf(b.y) << 16);
            v.w = f2bf(b.z) | (f2bf(b.w) << 16);
            int byte = (r * KB + kg * 16) ^ ((r & 7) << 4);
            *(uint4*)((char*)Alds + byte) = v;
        }
    } else {
        const int KG = K / 8;
        for (int idx = t; idx < 64 * KG; idx += 256) {
            int r = idx / KG, kg = idx % KG;
            int rr = row0 + r;
            if (rr >= N_NODES) rr = N_NODES - 1;
            uint4 v = *(const uint4*)(h + (size_t)rr * K + kg * 8);
            int byte = (r * KB + kg * 16) ^ ((r & 7) << 4);
            *(uint4*)((char*)Alds + byte) = v;
        }
    }
    __syncthreads();

    int w = t >> 6, l = t & 63;
    int lr = l & 15, lg = l >> 4;
    f32x4 acc[4];
#pragma unroll
    for (int nt = 0; nt < 4; nt++) {
        float s = shW[nt * 16 + lr];
        acc[nt] = (f32x4){s, s, s, s};
    }
#pragma unroll
    for (int c = 0; c < K / 32; c++) {
        int arow = w * 16 + lr;
        int abyte = (arow * KB + c * 64 + lg * 16) ^ ((arow & 7) << 4);
        bf16x8 a = *(const bf16x8*)((const char*)Alds + abyte);
#pragma unroll
        for (int nt = 0; nt < 4; nt++) {
            int n = nt * 16 + lr;
            int bbyte = (n * KB + c * 64 + lg * 16) ^ ((n & 7) << 4);
            bf16x8 b = *(const bf16x8*)((const char*)Wt + bbyte);
            acc[nt] = __builtin_amdgcn_mfma_f32_16x16x32_bf16(a, b, acc[nt], 0, 0, 0);
        }
    }
    int wrow0 = row0 + w * 16;
    char* myA = (char*)Alds + w * 16 * KB;
    float4 dv = {0.f, 0.f, 0.f, 0.f};
    float bias_v[4];
    if (LAYER0) {
#pragma unroll
        for (int nt = 0; nt < 4; nt++) bias_v[nt] = bias[nt * 16 + lr];
    } else {
        int dbase = wrow0 + lg * 4;
        if (dbase > N_NODES - 4) dbase = N_NODES - 4;
        dv = *(const float4*)(dinv + dbase);
    }
    float dvv[4] = {dv.x, dv.y, dv.z, dv.w};
    float st1[4] = {0.f, 0.f, 0.f, 0.f}, st2[4] = {0.f, 0.f, 0.f, 0.f};
#pragma unroll
    for (int nt = 0; nt < 4; nt++) {
#pragma unroll
        for (int r = 0; r < 4; r++) {
            float v = acc[nt][r];
            if (LAYER0) {
                v = fmaxf(v + bias_v[nt], 0.f);
                if (wrow0 + lg * 4 + r < N_NODES) {
                    st1[nt] += v;
                    st2[nt] += v * v;
                }
            } else {
                v = v * dvv[r];
            }
            int rowl = lg * 4 + r;
            int byte = (rowl * 128 + (nt * 16 + lr) * 2) ^ ((rowl & 7) << 4);
            *(ushort*)(myA + byte) = (ushort)f2bf(v);
        }
    }
    {
        int rowl0 = l >> 3, kg0 = l & 7;
        int b0 = (rowl0 * 128 + kg0 * 16) ^ ((rowl0 & 7) << 4);
        int rowl1 = 8 + (l >> 3);
        int b1 = (rowl1 * 128 + kg0 * 16) ^ ((rowl1 & 7) << 4);
        uint4 v0 = *(uint4*)(myA + b0);
        uint4 v1 = *(uint4*)(myA + b1);
        size_t gg = (size_t)wrow0 * 128 + l * 16;
        if (wrow0 + rowl0 < N_NODES) *(uint4*)((char*)out + gg) = v0;
        if (wrow0 + rowl1 < N_NODES) *(uint4*)((char*)out + gg + 1024) = v1;
    }
    if (LAYER0) {
#pragma unroll
        for (int nt = 0; nt < 4; nt++) {
            st1[nt] += __shfl_xor(st1[nt], 16);
            st1[nt] += __shfl_xor(st1[nt], 32);
            st2[nt] += __shfl_xor(st2[nt], 16);
            st2[nt] += __shfl_xor(st2[nt], 32);
        }
        if (l < 16) {
#pragma unroll
            for (int nt = 0; nt < 4; nt++) {
                sred[w][nt * 16 + l] = st1[nt];
                sred[w][64 + nt * 16 + l] = st2[nt];
            }
        }
        __syncthreads();
        if (t < 128) {
            float v = sred[0][t] + sred[1][t] + sred[2][t] + sred[3][t];
            atomicAdd(&sums_out[t], v);
        }
    }
}

// ---------------- K_C: per-bucket CSR finalize || gemm0(+stats) ----------------
__global__ __launch_bounds__(256) void k_csr_gemm0(
    const int2* __restrict__ pairs, const int* __restrict__ cursor,
    const int* __restrict__ bucketBase, int* __restrict__ row_ptr,
    float* __restrict__ dinv, int* __restrict__ col,
    const float* __restrict__ x, const float* __restrict__ W0,
    const float* __restrict__ sums0, const float* __restrict__ gamma,
    const float* __restrict__ beta, const float* __restrict__ bias,
    ushort* __restrict__ h0, float* __restrict__ sums1) {
    if (blockIdx.x < NBKT) {
        __shared__ int cnt_l[256];
        __shared__ int sb[256];
        __shared__ int sbex[256];
        int b = blockIdx.x;
        int t = threadIdx.x;
        int n = cursor[b];
        int base = bucketBase[b];
        const int2* reg = pairs + (size_t)b * BSLOT;
        cnt_l[t] = 0;
        __syncthreads();
        int rk[16];
#pragma unroll
        for (int k = 0; k < 16; k++) {
            int e = k * 256 + t;
            if (e < n) {
                int2 p = reg[e];
                rk[k] = atomicAdd(&cnt_l[p.y & 255], 1);
            }
        }
        __syncthreads();
        int c = cnt_l[t];
        sb[t] = c;
        __syncthreads();
        int x2 = c;
        for (int off = 1; off < 256; off <<= 1) {
            int y = (t >= off) ? sb[t - off] : 0;
            __syncthreads();
            x2 += y;
            sb[t] = x2;
            __syncthreads();
        }
        sbex[t] = x2 - c;
        int i = b * 256 + t;
        if (i < N_NODES) {
            dinv[i] = rsqrtf((float)(c + 1));
            row_ptr[i] = base + x2 - c;
        }
        __syncthreads();
#pragma unroll
        for (int k = 0; k < 16; k++) {
            int e = k * 256 + t;
            if (e < n) {
                int2 p = reg[e];
                col[base + sbex[p.y & 255] + rk[k]] = p.x;
            }
        }
        return;
    }
    gemm_body<IN_F, true>(blockIdx.x - NBKT, nullptr, x, W0, sums0, gamma, beta, bias,
                          nullptr, h0, sums1);
}

__global__ __launch_bounds__(256) void k_gemm64(
    const ushort* __restrict__ h, const float* __restrict__ W,
    const float* __restrict__ sums, const float* __restrict__ gamma,
    const float* __restrict__ beta, const float* __restrict__ dinv,
    ushort* __restrict__ out) {
    gemm_body<HID, false>(blockIdx.x, h, nullptr, W, sums, gamma, beta, nullptr, dinv,
                          out, nullptr);
}

// ---------------- stats on bf16 h (C=64) ----------------
__global__ __launch_bounds__(256) void k_stats_h(const uint4* __restrict__ h4,
                                                 float* __restrict__ sums) {
    __shared__ float lds[4][8][16];
    int t = threadIdx.x;
    int cg = t & 7, rs = t >> 3;
    float s1[8], s2[8];
#pragma unroll
    for (int j = 0; j < 8; j++) { s1[j] = 0.f; s2[j] = 0.f; }
    for (int r = blockIdx.x * 32 + rs; r < N_NODES; r += gridDim.x * 32) {
        uint4 v = h4[(size_t)r * 8 + cg];
        float f;
        f = bflo(v.x); s1[0] += f; s2[0] += f * f;
        f = bfhi(v.x); s1[1] += f; s2[1] += f * f;
        f = bflo(v.y); s1[2] += f; s2[2] += f * f;
        f = bfhi(v.y); s1[3] += f; s2[3] += f * f;
        f = bflo(v.z); s1[4] += f; s2[4] += f * f;
        f = bfhi(v.z); s1[5] += f; s2[5] += f * f;
        f = bflo(v.w); s1[6] += f; s2[6] += f * f;
        f = bfhi(v.w); s1[7] += f; s2[7] += f * f;
    }
#pragma unroll
    for (int off = 8; off <= 32; off <<= 1) {
#pragma unroll
        for (int j = 0; j < 8; j++) {
            s1[j] += __shfl_xor(s1[j], off);
            s2[j] += __shfl_xor(s2[j], off);
        }
    }
    int w = t >> 6;
    if ((t & 63) < 8) {
#pragma unroll
        for (int j = 0; j < 8; j++) {
            lds[w][cg][j] = s1[j];
            lds[w][cg][8 + j] = s2[j];
        }
    }
    __syncthreads();
    if (t < 128) {
        int cg2 = t >> 4, k = t & 15;
        float v = lds[0][cg2][k] + lds[1][cg2][k] + lds[2][cg2][k] + lds[3][cg2][k];
        int col = cg2 * 8 + (k & 7);
        atomicAdd(&sums[(k >> 3) * 64 + col], v);
    }
}

// ---------------- per-node gather aggregation (bf16 rows, shfl-broadcast col) ----------------
template <bool OUT_BF16>
__global__ __launch_bounds__(256) void k_agg(const uint4* __restrict__ t4,
                                             const int* __restrict__ row_ptr,
                                             const int* __restrict__ col,
                                             const float* __restrict__ dinv,
                                             const float* __restrict__ bias,
                                             void* __restrict__ out) {
    int wid = (blockIdx.x * 256 + threadIdx.x) >> 6;
    int lane = threadIdx.x & 63;
    int g = lane >> 3, q = lane & 7;
    if (wid >= N_NODES) return;
    int e0 = row_ptr[wid], e1 = row_ptr[wid + 1];
    int deg = e1 - e0;
    int ce = e0 + lane;
    int cidx = col[(ce < e1) ? ce : 0];   // one coalesced load covers 64 edges
    float a[8] = {0.f, 0.f, 0.f, 0.f, 0.f, 0.f, 0.f, 0.f};
    uint4 selfv = {0, 0, 0, 0};
    if (g == 0) selfv = t4[(size_t)wid * 8 + q];
    int degc = deg < 64 ? deg : 64;
    for (int d = 0; d < degc; d += 32) {
        int s[4];
        bool val[4];
#pragma unroll
        for (int j = 0; j < 4; j++) {
            int idx = d + j * 8 + g;
            val[j] = idx < degc;
            s[j] = __shfl(cidx, idx & 63);
        }
        uint4 v[4];
#pragma unroll
        for (int j = 0; j < 4; j++)
            v[j] = t4[(size_t)(val[j] ? s[j] : wid) * 8 + q];  // 4 gathers in flight
#pragma unroll
        for (int j = 0; j < 4; j++) {
            if (val[j]) {
                a[0] += bflo(v[j].x); a[1] += bfhi(v[j].x);
                a[2] += bflo(v[j].y); a[3] += bfhi(v[j].y);
                a[4] += bflo(v[j].z); a[5] += bfhi(v[j].z);
                a[6] += bflo(v[j].w); a[7] += bfhi(v[j].w);
            }
        }
    }
    for (int base = e0 + 64; base < e1; base += 8) {
        int ee = base + g;
        if (ee < e1) {
            int s = col[ee];
            uint4 v = t4[(size_t)s * 8 + q];
            a[0] += bflo(v.x); a[1] += bfhi(v.x);
            a[2] += bflo(v.y); a[3] += bfhi(v.y);
            a[4] += bflo(v.z); a[5] += bfhi(v.z);
            a[6] += bflo(v.w); a[7] += bfhi(v.w);
        }
    }
    if (g == 0) {
        a[0] += bflo(selfv.x); a[1] += bfhi(selfv.x);
        a[2] += bflo(selfv.y); a[3] += bfhi(selfv.y);
        a[4] += bflo(selfv.z); a[5] += bfhi(selfv.z);
        a[6] += bflo(selfv.w); a[7] += bfhi(selfv.w);
    }
#pragma unroll
    for (int off = 8; off <= 32; off <<= 1) {
#pragma unroll
        for (int j = 0; j < 8; j++) a[j] += __shfl_xor(a[j], off);
    }
    if (g == 0) {
        float di = dinv[wid];
        float4 b0v = reinterpret_cast<const float4*>(bias)[q * 2];
        float4 b1v = reinterpret_cast<const float4*>(bias)[q * 2 + 1];
        float r[8];
        r[0] = fmaxf(di * a[0] + b0v.x, 0.f);
        r[1] = fmaxf(di * a[1] + b0v.y, 0.f);
        r[2] = fmaxf(di * a[2] + b0v.z, 0.f);
        r[3] = fmaxf(di * a[3] + b0v.w, 0.f);
        r[4] = fmaxf(di * a[4] + b1v.x, 0.f);
        r[5] = fmaxf(di * a[5] + b1v.y, 0.f);
        r[6] = fmaxf(di * a[6] + b1v.z, 0.f);
        r[7] = fmaxf(di * a[7] + b1v.w, 0.f);
        if (OUT_BF16) {
            uint4 o;
            o.x = f2bf(r[0]) | (f2bf(r[1]) << 16);
            o.y = f2bf(r[2]) | (f2bf(r[3]) << 16);
            o.z = f2bf(r[4]) | (f2bf(r[5]) << 16);
            o.w = f2bf(r[6]) | (f2bf(r[7]) << 16);
            ((uint4*)out)[(size_t)wid * 8 + q] = o;
        } else {
            float4* orow = (float4*)((float*)out + (size_t)wid * HID + q * 8);
            orow[0] = (float4){r[0], r[1], r[2], r[3]};
            orow[1] = (float4){r[4], r[5], r[6], r[7]};
        }
    }
}

// ---------------- launch ----------------

extern "C" void kernel_launch(void* const* d_in, const int* in_sizes, int n_in,
                              void* d_out, int out_size, void* d_ws, size_t ws_size,
                              hipStream_t stream) {
    const float* x = (const float*)d_in[0];
    const int* ei = (const int*)d_in[1];
    const int4* src4 = (const int4*)ei;
    const int4* dst4 = (const int4*)(ei + N_EDGES);
    const float* bn0_g = (const float*)d_in[2];
    const float* bn0_b = (const float*)d_in[3];
    const float* W0 = (const float*)d_in[4];
    const float* b0 = (const float*)d_in[5];
    const float* bns_g = (const float*)d_in[6];
    const float* bns_b = (const float*)d_in[7];
    const float* Ws = (const float*)d_in[8];
    const float* bs = (const float*)d_in[9];
    float* out = (float*)d_out;
    char* ws = (char*)d_ws;

    // workspace layout (bytes)
    float*  dinv    = (float*)(ws + 0);          //   400,128
    int*    row_ptr = (int*)(ws + 400128);       //   400,384
    int*    col     = (int*)(ws + 800512);       // 4,800,000
    int*    cursor  = (int*)(ws + 5600512);      //     1,568 (pad 1,600)
    float*  sums    = (float*)(ws + 5602112);    //     2,560
    int*    bktBase = (int*)(ws + 5604672);      //     1,568
    int2*   pairs   = (int2*)(ws + 5606240);     // 12,812,288
    ushort* h0      = (ushort*)(ws + 18418528);  // 12,800,000
    ushort* h1      = (ushort*)(ws + 31218528);  // 12,800,000
    ushort* tbuf    = (ushort*)(ws + 44018528);  // 12,800,000 -> 56.8MB total
    ushort* h2      = h0;                        // h0 dead after gemm1
    float* sums0 = sums;          // 256 floats (IN_F)
    float* sums1 = sums + 256;    // 128
    float* sums2 = sums + 384;    // 128
    float* sums3 = sums + 512;    // 128

    const int AGG_B = (N_NODES + 3) / 4;      // 25000

    // zero cursor + sums in one memset (contiguous region)
    hipMemsetAsync(cursor, 0, 1600 + 640 * sizeof(float), stream);

    // ---- K_B: bucket counting-sort scatter || stats(x) ----
    k_bucket_stats<<<NBB + SB, 256, 0, stream>>>(src4, dst4, cursor, pairs,
                                                 (const float4*)x, sums0);
    // ---- bucket-total scan (1 block) ----
    k_scan_bkt<<<1, 512, 0, stream>>>(cursor, bktBase, row_ptr);

    // ---- K_C: per-bucket CSR finalize || gemm0 (BN+Linear+ReLU -> h0, stats -> sums1) ----
    k_csr_gemm0<<<NBKT + GEMM_B, 256, 0, stream>>>(pairs, cursor, bktBase, row_ptr, dinv,
                                                   col, x, W0, sums0, bn0_g, bn0_b, b0,
                                                   h0, sums1);

    // ---- layer 1 ----
    k_gemm64<<<GEMM_B, 256, 0, stream>>>(h0, Ws, sums1, bns_g, bns_b, dinv, tbuf);
    k_agg<true><<<AGG_B, 256, 0, stream>>>((const uint4*)tbuf, row_ptr, col, dinv, bs, h1);

    // ---- layer 2 ----
    k_stats_h<<<400, 256, 0, stream>>>((const uint4*)h1, sums2);
    k_gemm64<<<GEMM_B, 256, 0, stream>>>(h1, Ws + HID * HID, sums2, bns_g + HID,
                                         bns_b + HID, dinv, tbuf);
    k_agg<true><<<AGG_B, 256, 0, stream>>>((const uint4*)tbuf, row_ptr, col, dinv,
                                           bs + HID, h2);

    // ---- layer 3 (f32 out) ----
    k_stats_h<<<400, 256, 0, stream>>>((const uint4*)h2, sums3);
    k_gemm64<<<GEMM_B, 256, 0, stream>>>(h2, Ws + 2 * HID * HID, sums3, bns_g + 2 * HID,
                                         bns_b + 2 * HID, dinv, tbuf);
    k_agg<false><<<AGG_B, 256, 0, stream>>>((const uint4*)tbuf, row_ptr, col, dinv,
                                            bs + 2 * HID, out);
}